// Round 1
// baseline (1752.917 us; speedup 1.0000x reference)
//
#include <hip/hip_runtime.h>
#include <hip/hip_bf16.h>

typedef short short8 __attribute__((ext_vector_type(8)));
typedef float f32x4 __attribute__((ext_vector_type(4)));

#define DEV __device__ __forceinline__

// ---------------------------------------------------------------- async 16B global->LDS
DEV void async_load16(const void* g, void* l) {
    __builtin_amdgcn_global_load_lds(
        (const __attribute__((address_space(1))) unsigned int*)g,
        (__attribute__((address_space(3))) unsigned int*)l, 16, 0, 0);
}

// ---------------------------------------------------------------- f32 -> bf16 cast
__global__ __launch_bounds__(256) void cast_bf16_kernel(const float* __restrict__ in,
                                                        __hip_bfloat16* __restrict__ out, int n) {
    int i = (blockIdx.x * 256 + threadIdx.x) * 4;
    if (i < n) {
        float4 v = *(const float4*)&in[i];
        out[i + 0] = __float2bfloat16(v.x);
        out[i + 1] = __float2bfloat16(v.y);
        out[i + 2] = __float2bfloat16(v.z);
        out[i + 3] = __float2bfloat16(v.w);
    }
}

// ---------------------------------------------------------------- bf16 MFMA GEMM, C = A(M,K) * B(N,K)^T
// m97-style: 128x128 tile, BK=32, 4 waves (2x2), 4x4 16x16x32 frags per wave.
// EPI: 0 = store f32, 1 = store sigmoid(v + bias[n])
template <int EPI>
__global__ __launch_bounds__(256) void gemm_nt(const short* __restrict__ A,
                                               const short* __restrict__ Bm,
                                               float* __restrict__ C,
                                               const float* __restrict__ bias,
                                               int M, int N, int K) {
    __shared__ short lda[128 * 32];
    __shared__ short ldb[128 * 32];
    const int tid  = threadIdx.x;
    const int lane = tid & 63;
    const int wave = tid >> 6;
    const int m0 = blockIdx.x * 128;
    const int n0 = blockIdx.y * 128;
    const int wm = (wave >> 1) * 64;
    const int wn = (wave & 1) * 64;
    f32x4 acc[4][4] = {};

    const int sr = tid >> 2;        // 0..63  (staging row)
    const int sc = (tid & 3) * 8;   // 0,8,16,24 (staging col, bf16 elems)
    const short* Ab  = A  + (size_t)(m0 + sr) * K + sc;
    const short* Ab2 = Ab + (size_t)64 * K;
    const short* Bb  = Bm + (size_t)(n0 + sr) * K + sc;
    const short* Bb2 = Bb + (size_t)64 * K;
    short* la  = &lda[tid * 8];
    short* la2 = &lda[(tid + 256) * 8];
    short* lb  = &ldb[tid * 8];
    short* lb2 = &ldb[(tid + 256) * 8];

    const int fk = (lane >> 4) * 8;  // k-offset of fragment (contiguous 8, m97-verified)
    const int fr = lane & 15;        // row (A) / col (B) within 16x16 frag

    for (int k0 = 0; k0 < K; k0 += 32) {
        async_load16(Ab + k0,  la);
        async_load16(Ab2 + k0, la2);
        async_load16(Bb + k0,  lb);
        async_load16(Bb2 + k0, lb2);
        __syncthreads();
        short8 af[4], bfr[4];
#pragma unroll
        for (int i = 0; i < 4; i++) af[i]  = *(const short8*)&lda[(wm + i * 16 + fr) * 32 + fk];
#pragma unroll
        for (int j = 0; j < 4; j++) bfr[j] = *(const short8*)&ldb[(wn + j * 16 + fr) * 32 + fk];
#pragma unroll
        for (int i = 0; i < 4; i++)
#pragma unroll
            for (int j = 0; j < 4; j++)
                acc[i][j] = __builtin_amdgcn_mfma_f32_16x16x32_bf16(af[i], bfr[j], acc[i][j], 0, 0, 0);
        __syncthreads();
    }

    const int er = (lane >> 4) * 4;  // C/D: row = (lane>>4)*4 + reg, col = lane&15 (m89-verified)
    const int ec = lane & 15;
#pragma unroll
    for (int i = 0; i < 4; i++) {
        const int gr = m0 + wm + i * 16 + er;
#pragma unroll
        for (int j = 0; j < 4; j++) {
            const int gc = n0 + wn + j * 16 + ec;
            float bia = 0.f;
            if constexpr (EPI == 1) bia = bias[gc];
#pragma unroll
            for (int r = 0; r < 4; r++) {
                float v = acc[i][j][r];
                if constexpr (EPI == 1) v = 1.f / (1.f + __expf(-(v + bia)));
                C[(size_t)(gr + r) * N + gc] = v;
            }
        }
    }
}

// ---------------------------------------------------------------- l2norm over rows of 128 (in-place)
__global__ __launch_bounds__(256) void l2norm_kernel(float* __restrict__ buf) {
    const int row  = blockIdx.x * 4 + (threadIdx.x >> 6);
    const int lane = threadIdx.x & 63;
    float* p = &buf[(size_t)row * 128 + lane * 2];
    float2 v = *(float2*)p;
    float s = v.x * v.x + v.y * v.y;
#pragma unroll
    for (int off = 1; off < 64; off <<= 1) s += __shfl_xor(s, off);
    const float inv = 1.f / fmaxf(sqrtf(s), 1e-12f);
    v.x *= inv; v.y *= inv;
    *(float2*)p = v;
}

// ---------------------------------------------------------------- beta = sigmoid(x @ Wb^T + bb), f32 exact
__global__ __launch_bounds__(256) void beta_kernel(const float* __restrict__ x,
                                                   const float* __restrict__ Wb,
                                                   const float* __restrict__ bb,
                                                   float* __restrict__ beta) {
    __shared__ float xs[16 * 132];  // padded stride to kill bank conflicts
    const int tid = threadIdx.x;
    const float* xr = &x[(size_t)blockIdx.x * 2048];
#pragma unroll
    for (int i = tid; i < 512; i += 256) {
        float4 v = ((const float4*)xr)[i];
        const int j = i * 4;
        *(float4*)&xs[(j >> 7) * 132 + (j & 127)] = v;
    }
    __syncthreads();
    const int n = tid >> 4, ks = tid & 15;
    const float* w  = &Wb[(size_t)n * 2048 + ks * 128];
    const float* xx = &xs[ks * 132];  // note: col index below uses 128-chunk within padded row
    float s = 0.f;
#pragma unroll 8
    for (int j = 0; j < 128; j++) s += xx[j] * w[j];
    s += __shfl_xor(s, 1); s += __shfl_xor(s, 2);
    s += __shfl_xor(s, 4); s += __shfl_xor(s, 8);
    if (ks == 0) beta[(size_t)blockIdx.x * 16 + n] = 1.f / (1.f + __expf(-(s + bb[n])));
}

// ---------------------------------------------------------------- sequential recurrence
// 256 WGs: (b,h) x 8 row-blocks of 16 rows. 256 thr: row r = tid>>4, col-chunk c = tid&15 (8 f32 state).
__global__ __launch_bounds__(256) void recurrence_kernel(
        const float* __restrict__ S0, const float* __restrict__ qn, const float* __restrict__ kn,
        const float* __restrict__ vv, const float* __restrict__ aa, const float* __restrict__ bet,
        const float* __restrict__ gg, __hip_bfloat16* __restrict__ o) {
    const int wg = blockIdx.x;
    const int bh = wg >> 3;
    const int b = bh >> 4, h = bh & 15;
    const int rb = wg & 7;
    const int tid = threadIdx.x;
    const int r = tid >> 4;
    const int i = rb * 16 + r;
    const int c = tid & 15;
    __shared__ float kq[2][256];

    float S[8];
    {
        const float* s0 = &S0[((size_t)bh * 128 + i) * 128 + c * 8];
#pragma unroll
        for (int j = 0; j < 8; j++) S[j] = s0[j];
    }
    // prologue: stage t=0
    const size_t base0 = ((size_t)(b * 2048) * 16 + h) * 128;
    float stg = (tid < 128) ? kn[base0 + tid] : qn[base0 + tid - 128];
    kq[0][tid] = stg;
    float vi = vv[base0 + i];
    float ai = aa[base0 + i];
    float bt = bet[(size_t)(b * 2048) * 16 + h];
    float gi = gg[base0 + i];
    __syncthreads();

    for (int t = 0; t < 2048; ++t) {
        // prefetch t+1 (clamped; redundant at last step)
        const int tn = (t < 2047) ? t + 1 : 2047;
        const size_t basen = ((size_t)(b * 2048 + tn) * 16 + h) * 128;
        const float stg2 = (tid < 128) ? kn[basen + tid] : qn[basen + tid - 128];
        const float vi2 = vv[basen + i];
        const float ai2 = aa[basen + i];
        const float bt2 = bet[(size_t)(b * 2048 + tn) * 16 + h];
        const float gi2 = gg[basen + i];

        const int cur = t & 1;
        float kk[8], qq[8];
        *(float4*)&kk[0] = *(const float4*)&kq[cur][c * 8];
        *(float4*)&kk[4] = *(const float4*)&kq[cur][c * 8 + 4];

        float p = S[0] * kk[0];
#pragma unroll
        for (int j = 1; j < 8; j++) p += S[j] * kk[j];
        p += __shfl_xor(p, 1); p += __shfl_xor(p, 2);
        p += __shfl_xor(p, 4); p += __shfl_xor(p, 8);

        const float coef = bt * (vi - p);
#pragma unroll
        for (int j = 0; j < 8; j++) S[j] = ai * S[j] + coef * kk[j];

        *(float4*)&qq[0] = *(const float4*)&kq[cur][128 + c * 8];
        *(float4*)&qq[4] = *(const float4*)&kq[cur][128 + c * 8 + 4];
        float ov = S[0] * qq[0];
#pragma unroll
        for (int j = 1; j < 8; j++) ov += S[j] * qq[j];
        ov += __shfl_xor(ov, 1); ov += __shfl_xor(ov, 2);
        ov += __shfl_xor(ov, 4); ov += __shfl_xor(ov, 8);

        if (c == 0) {
            const size_t base = ((size_t)(b * 2048 + t) * 16 + h) * 128;
            o[base + i] = __float2bfloat16(ov * gi);
        }
        kq[cur ^ 1][tid] = stg2;
        vi = vi2; ai = ai2; bt = bt2; gi = gi2;
        __syncthreads();
    }
}

// ----------------------------------------------------------------
extern "C" void kernel_launch(void* const* d_in, const int* in_sizes, int n_in,
                              void* d_out, int out_size, void* d_ws, size_t ws_size,
                              hipStream_t stream) {
    const float* x  = (const float*)d_in[0];
    const float* S0 = (const float*)d_in[1];
    const float* Wq = (const float*)d_in[2];
    const float* Wk = (const float*)d_in[3];
    const float* Wv = (const float*)d_in[4];
    const float* Wa = (const float*)d_in[5];
    const float* ba = (const float*)d_in[6];
    const float* Wb = (const float*)d_in[7];
    const float* bb = (const float*)d_in[8];
    const float* Wg = (const float*)d_in[9];
    const float* bg = (const float*)d_in[10];
    const float* Wo = (const float*)d_in[11];
    float* out = (float*)d_out;

    const int M = 4096, N = 2048, K = 2048;

    size_t off = 0;
    auto alloc = [&](size_t bytes) {
        void* p = (char*)d_ws + off;
        off += (bytes + 255) & ~(size_t)255;
        return p;
    };
    short* x_bf  = (short*)alloc((size_t)M * K * 2);  // later reused as o_bf
    short* Wq_bf = (short*)alloc((size_t)N * K * 2);
    short* Wk_bf = (short*)alloc((size_t)N * K * 2);
    short* Wv_bf = (short*)alloc((size_t)N * K * 2);
    short* Wa_bf = (short*)alloc((size_t)N * K * 2);
    short* Wg_bf = (short*)alloc((size_t)N * K * 2);
    short* Wo_bf = (short*)alloc((size_t)N * K * 2);
    float* qb    = (float*)alloc((size_t)M * N * 4);
    float* kb    = (float*)alloc((size_t)M * N * 4);
    float* vb    = (float*)alloc((size_t)M * N * 4);
    float* ab    = (float*)alloc((size_t)M * N * 4);
    float* gb    = (float*)alloc((size_t)M * N * 4);
    float* betab = (float*)alloc((size_t)M * 16 * 4);

    // casts
    cast_bf16_kernel<<<dim3((M * K / 4 + 255) / 256), dim3(256), 0, stream>>>(x,  (__hip_bfloat16*)x_bf,  M * K);
    cast_bf16_kernel<<<dim3((N * K / 4 + 255) / 256), dim3(256), 0, stream>>>(Wq, (__hip_bfloat16*)Wq_bf, N * K);
    cast_bf16_kernel<<<dim3((N * K / 4 + 255) / 256), dim3(256), 0, stream>>>(Wk, (__hip_bfloat16*)Wk_bf, N * K);
    cast_bf16_kernel<<<dim3((N * K / 4 + 255) / 256), dim3(256), 0, stream>>>(Wv, (__hip_bfloat16*)Wv_bf, N * K);
    cast_bf16_kernel<<<dim3((N * K / 4 + 255) / 256), dim3(256), 0, stream>>>(Wa, (__hip_bfloat16*)Wa_bf, N * K);
    cast_bf16_kernel<<<dim3((N * K / 4 + 255) / 256), dim3(256), 0, stream>>>(Wg, (__hip_bfloat16*)Wg_bf, N * K);
    cast_bf16_kernel<<<dim3((N * K / 4 + 255) / 256), dim3(256), 0, stream>>>(Wo, (__hip_bfloat16*)Wo_bf, N * K);

    // projections
    dim3 gdim(M / 128, N / 128), bdim(256);
    gemm_nt<0><<<gdim, bdim, 0, stream>>>(x_bf, Wq_bf, qb, nullptr, M, N, K);
    gemm_nt<0><<<gdim, bdim, 0, stream>>>(x_bf, Wk_bf, kb, nullptr, M, N, K);
    gemm_nt<0><<<gdim, bdim, 0, stream>>>(x_bf, Wv_bf, vb, nullptr, M, N, K);
    gemm_nt<1><<<gdim, bdim, 0, stream>>>(x_bf, Wa_bf, ab, ba, M, N, K);
    gemm_nt<1><<<gdim, bdim, 0, stream>>>(x_bf, Wg_bf, gb, bg, M, N, K);

    l2norm_kernel<<<dim3(M * 16 / 4), dim3(256), 0, stream>>>(qb);
    l2norm_kernel<<<dim3(M * 16 / 4), dim3(256), 0, stream>>>(kb);
    beta_kernel<<<dim3(M), dim3(256), 0, stream>>>(x, Wb, bb, betab);

    // recurrence: writes o (bf16) over x_bf region (x_bf dead after projections)
    __hip_bfloat16* o_bf = (__hip_bfloat16*)x_bf;
    recurrence_kernel<<<dim3(256), dim3(256), 0, stream>>>(S0, qb, kb, vb, ab, betab, gb, o_bf);

    // out = (o*g) @ Wo^T
    gemm_nt<0><<<gdim, bdim, 0, stream>>>((const short*)o_bf, Wo_bf, out, nullptr, M, N, K);
}

// Round 2
// 1429.108 us; speedup vs baseline: 1.2266x; 1.2266x over previous
//
#include <hip/hip_runtime.h>
#include <hip/hip_bf16.h>

typedef short short8 __attribute__((ext_vector_type(8)));
typedef float f32x4 __attribute__((ext_vector_type(4)));

#define DEV __device__ __forceinline__

// ---------------------------------------------------------------- async 16B global->LDS
DEV void async_load16(const void* g, void* l) {
    __builtin_amdgcn_global_load_lds(
        (const __attribute__((address_space(1))) unsigned int*)g,
        (__attribute__((address_space(3))) unsigned int*)l, 16, 0, 0);
}

// ---------------------------------------------------------------- f32 -> bf16 cast
__global__ __launch_bounds__(256) void cast_bf16_kernel(const float* __restrict__ in,
                                                        __hip_bfloat16* __restrict__ out, int n) {
    int i = (blockIdx.x * 256 + threadIdx.x) * 4;
    if (i < n) {
        float4 v = *(const float4*)&in[i];
        out[i + 0] = __float2bfloat16(v.x);
        out[i + 1] = __float2bfloat16(v.y);
        out[i + 2] = __float2bfloat16(v.z);
        out[i + 3] = __float2bfloat16(v.w);
    }
}

// ---------------------------------------------------------------- bf16 MFMA GEMM, C = A(M,K) * B(N,K)^T
// m97-style: 128x128 tile, BK=32, 4 waves (2x2), 4x4 16x16x32 frags per wave.
// EPI: 0 = store f32, 1 = store sigmoid(v + bias[n])
template <int EPI>
__global__ __launch_bounds__(256) void gemm_nt(const short* __restrict__ A,
                                               const short* __restrict__ Bm,
                                               float* __restrict__ C,
                                               const float* __restrict__ bias,
                                               int M, int N, int K) {
    __shared__ short lda[128 * 32];
    __shared__ short ldb[128 * 32];
    const int tid  = threadIdx.x;
    const int lane = tid & 63;
    const int wave = tid >> 6;
    const int m0 = blockIdx.x * 128;
    const int n0 = blockIdx.y * 128;
    const int wm = (wave >> 1) * 64;
    const int wn = (wave & 1) * 64;
    f32x4 acc[4][4] = {};

    const int sr = tid >> 2;        // 0..63  (staging row)
    const int sc = (tid & 3) * 8;   // 0,8,16,24 (staging col, bf16 elems)
    const short* Ab  = A  + (size_t)(m0 + sr) * K + sc;
    const short* Ab2 = Ab + (size_t)64 * K;
    const short* Bb  = Bm + (size_t)(n0 + sr) * K + sc;
    const short* Bb2 = Bb + (size_t)64 * K;
    short* la  = &lda[tid * 8];
    short* la2 = &lda[(tid + 256) * 8];
    short* lb  = &ldb[tid * 8];
    short* lb2 = &ldb[(tid + 256) * 8];

    const int fk = (lane >> 4) * 8;  // k-offset of fragment
    const int fr = lane & 15;        // row (A) / col (B) within 16x16 frag

    for (int k0 = 0; k0 < K; k0 += 32) {
        async_load16(Ab + k0,  la);
        async_load16(Ab2 + k0, la2);
        async_load16(Bb + k0,  lb);
        async_load16(Bb2 + k0, lb2);
        __syncthreads();
        short8 af[4], bfr[4];
#pragma unroll
        for (int i = 0; i < 4; i++) af[i]  = *(const short8*)&lda[(wm + i * 16 + fr) * 32 + fk];
#pragma unroll
        for (int j = 0; j < 4; j++) bfr[j] = *(const short8*)&ldb[(wn + j * 16 + fr) * 32 + fk];
#pragma unroll
        for (int i = 0; i < 4; i++)
#pragma unroll
            for (int j = 0; j < 4; j++)
                acc[i][j] = __builtin_amdgcn_mfma_f32_16x16x32_bf16(af[i], bfr[j], acc[i][j], 0, 0, 0);
        __syncthreads();
    }

    const int er = (lane >> 4) * 4;  // C/D: row = (lane>>4)*4 + reg, col = lane&15
    const int ec = lane & 15;
#pragma unroll
    for (int i = 0; i < 4; i++) {
        const int gr = m0 + wm + i * 16 + er;
#pragma unroll
        for (int j = 0; j < 4; j++) {
            const int gc = n0 + wn + j * 16 + ec;
            float bia = 0.f;
            if constexpr (EPI == 1) bia = bias[gc];
#pragma unroll
            for (int r = 0; r < 4; r++) {
                float v = acc[i][j][r];
                if constexpr (EPI == 1) v = 1.f / (1.f + __expf(-(v + bia)));
                C[(size_t)(gr + r) * N + gc] = v;
            }
        }
    }
}

// ---------------------------------------------------------------- l2norm over rows of 128 (in-place)
__global__ __launch_bounds__(256) void l2norm_kernel(float* __restrict__ buf) {
    const int row  = blockIdx.x * 4 + (threadIdx.x >> 6);
    const int lane = threadIdx.x & 63;
    float* p = &buf[(size_t)row * 128 + lane * 2];
    float2 v = *(float2*)p;
    float s = v.x * v.x + v.y * v.y;
#pragma unroll
    for (int off = 1; off < 64; off <<= 1) s += __shfl_xor(s, off);
    const float inv = 1.f / fmaxf(sqrtf(s), 1e-12f);
    v.x *= inv; v.y *= inv;
    *(float2*)p = v;
}

// ---------------------------------------------------------------- beta = sigmoid(x @ Wb^T + bb), f32 exact
__global__ __launch_bounds__(256) void beta_kernel(const float* __restrict__ x,
                                                   const float* __restrict__ Wb,
                                                   const float* __restrict__ bb,
                                                   float* __restrict__ beta) {
    __shared__ float xs[16 * 132];
    const int tid = threadIdx.x;
    const float* xr = &x[(size_t)blockIdx.x * 2048];
#pragma unroll
    for (int i = tid; i < 512; i += 256) {
        float4 v = ((const float4*)xr)[i];
        const int j = i * 4;
        *(float4*)&xs[(j >> 7) * 132 + (j & 127)] = v;
    }
    __syncthreads();
    const int n = tid >> 4, ks = tid & 15;
    const float* w  = &Wb[(size_t)n * 2048 + ks * 128];
    const float* xx = &xs[ks * 132];
    float s = 0.f;
#pragma unroll 8
    for (int j = 0; j < 128; j++) s += xx[j] * w[j];
    s += __shfl_xor(s, 1); s += __shfl_xor(s, 2);
    s += __shfl_xor(s, 4); s += __shfl_xor(s, 8);
    if (ks == 0) beta[(size_t)blockIdx.x * 16 + n] = 1.f / (1.f + __expf(-(s + bb[n])));
}

// ---------------------------------------------------------------- sequential recurrence, wave-private
// 1024 waves (256 WG x 4 waves). wave = 4 rows x 16 lanes; 8 state f32/lane.
// No LDS, no barriers: k/q loaded to regs per wave (dup addrs coalesce),
// 4-level shfl_xor reduce within the 16-lane row group, 2-deep ping-pong prefetch.
__global__ __launch_bounds__(256) void recurrence_kernel(
        const float* __restrict__ S0, const float* __restrict__ qn, const float* __restrict__ kn,
        const float* __restrict__ vv, const float* __restrict__ adec, const float* __restrict__ bet,
        const float* __restrict__ gg, __hip_bfloat16* __restrict__ o) {
    const int wid = blockIdx.x * 4 + (threadIdx.x >> 6);  // 0..1023
    const int bh  = wid >> 5;                             // 0..31
    const int rb  = wid & 31;                             // row block (4 rows)
    const int b = bh >> 4, h = bh & 15;
    const int lane = threadIdx.x & 63;
    const int r = lane >> 4;          // row within wave
    const int i = rb * 4 + r;         // 0..127
    const int c = lane & 15;          // col chunk (8 f32)

    float S[8];
    {
        const float* s0 = &S0[((size_t)bh * 128 + i) * 128 + c * 8];
        *(float4*)&S[0] = *(const float4*)&s0[0];
        *(float4*)&S[4] = *(const float4*)&s0[4];
    }

    const size_t hb = (size_t)(b * 2048) * 16 + h;   // (b,t=0,h) row index
    const size_t step = 16 * 128;                    // elems per t in (B,T,H,D) arrays
    const float* kp = kn + hb * 128 + c * 8;
    const float* qp = qn + hb * 128 + c * 8;
    const float* vp = vv   + hb * 128 + i;
    const float* ap = adec + hb * 128 + i;
    const float* gp = gg   + hb * 128 + i;
    const float* bp = bet + hb;
    __hip_bfloat16* op = o + hb * 128 + i;

    // t=0 into set A
    float kA[8], qA[8], vA, aA, gA, bA;
    float kB[8], qB[8], vB, aB, gB, bB;
    *(float4*)&kA[0] = *(const float4*)(kp);     *(float4*)&kA[4] = *(const float4*)(kp + 4);
    *(float4*)&qA[0] = *(const float4*)(qp);     *(float4*)&qA[4] = *(const float4*)(qp + 4);
    vA = *vp; aA = *ap; gA = *gp; bA = *bp;

#define RBODY(KC, QC, VC, AC, GC, BC, KN, QN, VN, AN, GN, BN, T)                          \
    do {                                                                                  \
        const int tn_ = ((T) + 1 < 2048) ? (T) + 1 : 2047;                                \
        const size_t nb_ = (size_t)tn_ * step;                                            \
        *(float4*)&KN[0] = *(const float4*)(kp + nb_);                                    \
        *(float4*)&KN[4] = *(const float4*)(kp + nb_ + 4);                                \
        *(float4*)&QN[0] = *(const float4*)(qp + nb_);                                    \
        *(float4*)&QN[4] = *(const float4*)(qp + nb_ + 4);                                \
        VN = vp[nb_]; AN = ap[nb_]; GN = gp[nb_]; BN = bp[(size_t)tn_ * 16];              \
        float p0 = S[0] * KC[0], p1 = S[1] * KC[1], p2 = S[2] * KC[2], p3 = S[3] * KC[3]; \
        p0 = fmaf(S[4], KC[4], p0); p1 = fmaf(S[5], KC[5], p1);                           \
        p2 = fmaf(S[6], KC[6], p2); p3 = fmaf(S[7], KC[7], p3);                           \
        float p = (p0 + p1) + (p2 + p3);                                                  \
        p += __shfl_xor(p, 1); p += __shfl_xor(p, 2);                                     \
        p += __shfl_xor(p, 4); p += __shfl_xor(p, 8);                                     \
        const float coef = BC * (VC - p);                                                 \
        _Pragma("unroll") for (int j = 0; j < 8; j++)                                     \
            S[j] = fmaf(AC, S[j], coef * KC[j]);                                          \
        float o0 = S[0] * QC[0], o1 = S[1] * QC[1], o2 = S[2] * QC[2], o3 = S[3] * QC[3]; \
        o0 = fmaf(S[4], QC[4], o0); o1 = fmaf(S[5], QC[5], o1);                           \
        o2 = fmaf(S[6], QC[6], o2); o3 = fmaf(S[7], QC[7], o3);                           \
        float ov = (o0 + o1) + (o2 + o3);                                                 \
        ov += __shfl_xor(ov, 1); ov += __shfl_xor(ov, 2);                                 \
        ov += __shfl_xor(ov, 4); ov += __shfl_xor(ov, 8);                                 \
        if (c == 0) op[(size_t)(T) * step] = __float2bfloat16(ov * GC);                   \
    } while (0)

    for (int t = 0; t < 2048; t += 2) {
        RBODY(kA, qA, vA, aA, gA, bA, kB, qB, vB, aB, gB, bB, t);
        RBODY(kB, qB, vB, aB, gB, bB, kA, qA, vA, aA, gA, bA, t + 1);
    }
#undef RBODY
}

// ----------------------------------------------------------------
extern "C" void kernel_launch(void* const* d_in, const int* in_sizes, int n_in,
                              void* d_out, int out_size, void* d_ws, size_t ws_size,
                              hipStream_t stream) {
    const float* x  = (const float*)d_in[0];
    const float* S0 = (const float*)d_in[1];
    const float* Wq = (const float*)d_in[2];
    const float* Wk = (const float*)d_in[3];
    const float* Wv = (const float*)d_in[4];
    const float* Wa = (const float*)d_in[5];
    const float* ba = (const float*)d_in[6];
    const float* Wb = (const float*)d_in[7];
    const float* bb = (const float*)d_in[8];
    const float* Wg = (const float*)d_in[9];
    const float* bg = (const float*)d_in[10];
    const float* Wo = (const float*)d_in[11];
    float* out = (float*)d_out;

    const int M = 4096, N = 2048, K = 2048;

    size_t off = 0;
    auto alloc = [&](size_t bytes) {
        void* p = (char*)d_ws + off;
        off += (bytes + 255) & ~(size_t)255;
        return p;
    };
    short* x_bf  = (short*)alloc((size_t)M * K * 2);  // later reused as o_bf
    short* Wq_bf = (short*)alloc((size_t)N * K * 2);
    short* Wk_bf = (short*)alloc((size_t)N * K * 2);
    short* Wv_bf = (short*)alloc((size_t)N * K * 2);
    short* Wa_bf = (short*)alloc((size_t)N * K * 2);
    short* Wg_bf = (short*)alloc((size_t)N * K * 2);
    short* Wo_bf = (short*)alloc((size_t)N * K * 2);
    float* qb    = (float*)alloc((size_t)M * N * 4);
    float* kb    = (float*)alloc((size_t)M * N * 4);
    float* vb    = (float*)alloc((size_t)M * N * 4);
    float* ab    = (float*)alloc((size_t)M * N * 4);
    float* gb    = (float*)alloc((size_t)M * N * 4);
    float* betab = (float*)alloc((size_t)M * 16 * 4);

    // casts
    cast_bf16_kernel<<<dim3((M * K / 4 + 255) / 256), dim3(256), 0, stream>>>(x,  (__hip_bfloat16*)x_bf,  M * K);
    cast_bf16_kernel<<<dim3((N * K / 4 + 255) / 256), dim3(256), 0, stream>>>(Wq, (__hip_bfloat16*)Wq_bf, N * K);
    cast_bf16_kernel<<<dim3((N * K / 4 + 255) / 256), dim3(256), 0, stream>>>(Wk, (__hip_bfloat16*)Wk_bf, N * K);
    cast_bf16_kernel<<<dim3((N * K / 4 + 255) / 256), dim3(256), 0, stream>>>(Wv, (__hip_bfloat16*)Wv_bf, N * K);
    cast_bf16_kernel<<<dim3((N * K / 4 + 255) / 256), dim3(256), 0, stream>>>(Wa, (__hip_bfloat16*)Wa_bf, N * K);
    cast_bf16_kernel<<<dim3((N * K / 4 + 255) / 256), dim3(256), 0, stream>>>(Wg, (__hip_bfloat16*)Wg_bf, N * K);
    cast_bf16_kernel<<<dim3((N * K / 4 + 255) / 256), dim3(256), 0, stream>>>(Wo, (__hip_bfloat16*)Wo_bf, N * K);

    // projections
    dim3 gdim(M / 128, N / 128), bdim(256);
    gemm_nt<0><<<gdim, bdim, 0, stream>>>(x_bf, Wq_bf, qb, nullptr, M, N, K);
    gemm_nt<0><<<gdim, bdim, 0, stream>>>(x_bf, Wk_bf, kb, nullptr, M, N, K);
    gemm_nt<0><<<gdim, bdim, 0, stream>>>(x_bf, Wv_bf, vb, nullptr, M, N, K);
    gemm_nt<1><<<gdim, bdim, 0, stream>>>(x_bf, Wa_bf, ab, ba, M, N, K);
    gemm_nt<1><<<gdim, bdim, 0, stream>>>(x_bf, Wg_bf, gb, bg, M, N, K);

    l2norm_kernel<<<dim3(M * 16 / 4), dim3(256), 0, stream>>>(qb);
    l2norm_kernel<<<dim3(M * 16 / 4), dim3(256), 0, stream>>>(kb);
    beta_kernel<<<dim3(M), dim3(256), 0, stream>>>(x, Wb, bb, betab);

    // recurrence: writes o (bf16) over x_bf region (x_bf dead after projections)
    __hip_bfloat16* o_bf = (__hip_bfloat16*)x_bf;
    recurrence_kernel<<<dim3(256), dim3(256), 0, stream>>>(S0, qb, kb, vb, ab, betab, gb, o_bf);

    // out = (o*g) @ Wo^T
    gemm_nt<0><<<gdim, bdim, 0, stream>>>((const short*)o_bf, Wo_bf, out, nullptr, M, N, K);
}